// Round 17
// baseline (153.677 us; speedup 1.0000x reference)
//
#include <hip/hip_runtime.h>
#include <math.h>

#define H 128
#define NF 100000
#define NC 25000
#define TM 64

typedef _Float16 f16;
typedef f16 f16x8 __attribute__((ext_vector_type(8)));
typedef f16 f16x4 __attribute__((ext_vector_type(4)));
typedef float f32x4 __attribute__((ext_vector_type(4)));

#define MFMA16(a, b, c) __builtin_amdgcn_mfma_f32_16x16x32_f16((a), (b), (c), 0, 0, 0)

// ws: fragment-ordered f16 weights (fragment = 64 lanes x 8 f16 = 1 KB contiguous)
//   F1 @ 0     : [nt=8][kk=8][lane=64][8]   W1^T, k<256 (kk 0..3 = xg half, 4..7 = xs half)
//   F2 @ 32768 : [nt=8][kk=4][lane=64][8]   W2^T
//   F3 @ 49152 : [nt=8][kk=4][lane=64][8]   W3^T
// fragment element: n = nt*16 + (lane&15), k = kk*32 + (lane>>4)*8 + j

__global__ void prep_w(const float* __restrict__ W1, const float* __restrict__ W2,
                       const float* __restrict__ W3, f16* __restrict__ ws)
{
    int i = blockIdx.x * 256 + threadIdx.x;   // 0..65535, grid exact
    if (i < 32768) {
        int j = i & 7, lane = (i >> 3) & 63, kk = (i >> 9) & 7, nt = i >> 12;
        int n = nt * 16 + (lane & 15);
        int k = kk * 32 + (lane >> 4) * 8 + j;
        ws[i] = (f16)W1[k * H + n];
    } else if (i < 49152) {
        int q = i - 32768;
        int j = q & 7, lane = (q >> 3) & 63, kk = (q >> 9) & 3, nt = q >> 11;
        int n = nt * 16 + (lane & 15);
        int k = kk * 32 + (lane >> 4) * 8 + j;
        ws[i] = (f16)W2[k * H + n];
    } else {
        int q = i - 49152;
        int j = q & 7, lane = (q >> 3) & 63, kk = (q >> 9) & 3, nt = q >> 11;
        int n = nt * 16 + (lane & 15);
        int k = kk * 32 + (lane >> 4) * 8 + j;
        ws[i] = (f16)W3[k * H + n];
    }
}

__device__ __forceinline__ float silu_f(float v) {
    return v / (1.0f + __expf(-v));
}

// R11 structure, single variable changed: __launch_bounds__ 2nd arg 4 -> 6.
// Empirical finding (R4/R6/R10/R11/R15/R16): delivered occupancy == arg blocks/CU;
// the arg acts as a residency cap via amdgpu-waves-per-eu. VGPR budget 512/6=85 >= 64 used.
__global__ __launch_bounds__(256, 6)
void fused_mlp_v17(const float* __restrict__ x,     // [2][25000][128]
                   const float* __restrict__ xsc,   // [2][100000][128]
                   const int*   __restrict__ f2c,   // [100000]
                   const float* __restrict__ dist,  // [100000]
                   const float* __restrict__ W1,    // [257][128] (row 256 used as f32)
                   const float* __restrict__ b1,
                   const float* __restrict__ b2,
                   const float* __restrict__ b3,
                   const f16*   __restrict__ ws,
                   float* __restrict__ out)         // [200000][128]
{
    __shared__ __align__(16) f16 sA[TM * H];         // 16 KB
    __shared__ float sD[TM];
    __shared__ int   sCI[TM];

    const int t = threadIdx.x;
    const int l = t & 63, w = t >> 6;
    const int wRow = (w >> 1) * 32;                  // 0 or 32
    const int wnt  = (w & 1) * 4;                    // first n-tile (of 8) for this wave
    const int lr = l & 15, lg = l >> 4;
    const int R0 = blockIdx.x * TM;

    // ---- per-row metadata ----
    if (t < TM) {
        int Rs = R0 + t;
        int bb = Rs >= NF;
        int nn = Rs - bb * NF;
        sCI[t] = bb * NC + f2c[nn];
        sD[t]  = dist[nn];
    }
    __syncthreads();                                 // B0: meta ready

    const f16* F1 = ws;
    const f16* F2 = ws + 32768;
    const f16* F3 = ws + 49152;

    // ---- acc init: b1 + d*W1[256] ----
    f32x4 acc[2][4];
    #pragma unroll
    for (int nt = 0; nt < 4; ++nt) {
        int col = (wnt + nt) * 16 + lr;
        float bc = b1[col];
        float wc = W1[256 * H + col];
        #pragma unroll
        for (int mt = 0; mt < 2; ++mt)
            #pragma unroll
            for (int r = 0; r < 4; ++r)
                acc[mt][nt][r] = bc + sD[wRow + mt * 16 + lg * 4 + r] * wc;
    }

    // ---- phase 1: stage xg (gathered coarse rows) ----
    #pragma unroll
    for (int i = 0; i < 8; ++i) {
        int f = i * 256 + t;
        int row = f >> 5, col = (f & 31) * 4;
        float4 v = *(const float4*)(x + (long long)sCI[row] * H + col);
        f16x4 hv; hv[0] = (f16)v.x; hv[1] = (f16)v.y; hv[2] = (f16)v.z; hv[3] = (f16)v.w;
        *(f16x4*)(sA + row * H + (((col >> 3) ^ (row & 7)) << 3) + (col & 7)) = hv;
    }
    __syncthreads();                                 // B1: xg ready

    // layer-1 half 0 (F1 kk=0..3)
    #pragma unroll
    for (int kk = 0; kk < 4; ++kk) {
        f16x8 wv[4];
        #pragma unroll
        for (int nt = 0; nt < 4; ++nt)
            wv[nt] = *(const f16x8*)(F1 + ((((wnt + nt) * 8 + kk) * 64 + l) << 3));
        int k = kk * 32 + (lg << 3);
        int slot = (((k >> 3) ^ (lr & 7)) << 3);
        f16x8 a0 = *(const f16x8*)(sA + (wRow + lr) * H + slot);
        f16x8 a1 = *(const f16x8*)(sA + (wRow + 16 + lr) * H + slot);
        #pragma unroll
        for (int nt = 0; nt < 4; ++nt) {
            acc[0][nt] = MFMA16(a0, wv[nt], acc[0][nt]);
            acc[1][nt] = MFMA16(a1, wv[nt], acc[1][nt]);
        }
    }
    __syncthreads();                                 // B2: xg reads done

    // ---- phase 2: stage xs into the same buffer ----
    #pragma unroll
    for (int i = 0; i < 8; ++i) {
        int f = i * 256 + t;
        int row = f >> 5, col = (f & 31) * 4;
        float4 v = *(const float4*)(xsc + (long long)(R0 + row) * H + col);
        f16x4 hv; hv[0] = (f16)v.x; hv[1] = (f16)v.y; hv[2] = (f16)v.z; hv[3] = (f16)v.w;
        *(f16x4*)(sA + row * H + (((col >> 3) ^ (row & 7)) << 3) + (col & 7)) = hv;
    }
    __syncthreads();                                 // B3: xs ready

    // layer-1 half 1 (F1 kk=4..7)
    #pragma unroll
    for (int kk = 0; kk < 4; ++kk) {
        f16x8 wv[4];
        #pragma unroll
        for (int nt = 0; nt < 4; ++nt)
            wv[nt] = *(const f16x8*)(F1 + ((((wnt + nt) * 8 + kk + 4) * 64 + l) << 3));
        int k = kk * 32 + (lg << 3);
        int slot = (((k >> 3) ^ (lr & 7)) << 3);
        f16x8 a0 = *(const f16x8*)(sA + (wRow + lr) * H + slot);
        f16x8 a1 = *(const f16x8*)(sA + (wRow + 16 + lr) * H + slot);
        #pragma unroll
        for (int nt = 0; nt < 4; ++nt) {
            acc[0][nt] = MFMA16(a0, wv[nt], acc[0][nt]);
            acc[1][nt] = MFMA16(a1, wv[nt], acc[1][nt]);
        }
    }
    __syncthreads();                                 // B4: xs reads done

    // h1 -> sA
    #pragma unroll
    for (int nt = 0; nt < 4; ++nt)
        #pragma unroll
        for (int mt = 0; mt < 2; ++mt)
            #pragma unroll
            for (int r = 0; r < 4; ++r) {
                int row = wRow + mt * 16 + lg * 4 + r;
                int col = (wnt + nt) * 16 + lr;
                sA[row * H + (((col >> 3) ^ (row & 7)) << 3) + (col & 7)] =
                    (f16)silu_f(acc[mt][nt][r]);
            }
    __syncthreads();                                 // B5: h1 ready

    // ---- layer 2 ----
    #pragma unroll
    for (int nt = 0; nt < 4; ++nt) {
        float bc = b2[(wnt + nt) * 16 + lr];
        #pragma unroll
        for (int mt = 0; mt < 2; ++mt)
            #pragma unroll
            for (int r = 0; r < 4; ++r)
                acc[mt][nt][r] = bc;
    }
    #pragma unroll
    for (int kk = 0; kk < 4; ++kk) {
        f16x8 wv[4];
        #pragma unroll
        for (int nt = 0; nt < 4; ++nt)
            wv[nt] = *(const f16x8*)(F2 + ((((wnt + nt) * 4 + kk) * 64 + l) << 3));
        int k = kk * 32 + (lg << 3);
        int slot = (((k >> 3) ^ (lr & 7)) << 3);
        f16x8 a0 = *(const f16x8*)(sA + (wRow + lr) * H + slot);
        f16x8 a1 = *(const f16x8*)(sA + (wRow + 16 + lr) * H + slot);
        #pragma unroll
        for (int nt = 0; nt < 4; ++nt) {
            acc[0][nt] = MFMA16(a0, wv[nt], acc[0][nt]);
            acc[1][nt] = MFMA16(a1, wv[nt], acc[1][nt]);
        }
    }
    __syncthreads();                                 // B6: h1 reads done

    // h2 -> sA
    #pragma unroll
    for (int nt = 0; nt < 4; ++nt)
        #pragma unroll
        for (int mt = 0; mt < 2; ++mt)
            #pragma unroll
            for (int r = 0; r < 4; ++r) {
                int row = wRow + mt * 16 + lg * 4 + r;
                int col = (wnt + nt) * 16 + lr;
                sA[row * H + (((col >> 3) ^ (row & 7)) << 3) + (col & 7)] =
                    (f16)silu_f(acc[mt][nt][r]);
            }
    __syncthreads();                                 // B7: h2 ready

    // ---- layer 3 ----
    #pragma unroll
    for (int nt = 0; nt < 4; ++nt) {
        float bc = b3[(wnt + nt) * 16 + lr];
        #pragma unroll
        for (int mt = 0; mt < 2; ++mt)
            #pragma unroll
            for (int r = 0; r < 4; ++r)
                acc[mt][nt][r] = bc;
    }
    #pragma unroll
    for (int kk = 0; kk < 4; ++kk) {
        f16x8 wv[4];
        #pragma unroll
        for (int nt = 0; nt < 4; ++nt)
            wv[nt] = *(const f16x8*)(F3 + ((((wnt + nt) * 4 + kk) * 64 + l) << 3));
        int k = kk * 32 + (lg << 3);
        int slot = (((k >> 3) ^ (lr & 7)) << 3);
        f16x8 a0 = *(const f16x8*)(sA + (wRow + lr) * H + slot);
        f16x8 a1 = *(const f16x8*)(sA + (wRow + 16 + lr) * H + slot);
        #pragma unroll
        for (int nt = 0; nt < 4; ++nt) {
            acc[0][nt] = MFMA16(a0, wv[nt], acc[0][nt]);
            acc[1][nt] = MFMA16(a1, wv[nt], acc[1][nt]);
        }
    }

    // ---- store out ----
    #pragma unroll
    for (int mt = 0; mt < 2; ++mt)
        #pragma unroll
        for (int nt = 0; nt < 4; ++nt)
            #pragma unroll
            for (int r = 0; r < 4; ++r) {
                long long row = (long long)R0 + wRow + mt * 16 + lg * 4 + r;
                int col = (wnt + nt) * 16 + lr;
                out[row * H + col] = acc[mt][nt][r];
            }
}

extern "C" void kernel_launch(void* const* d_in, const int* in_sizes, int n_in,
                              void* d_out, int out_size, void* d_ws, size_t ws_size,
                              hipStream_t stream)
{
    const float* x    = (const float*)d_in[0];
    const float* xsc  = (const float*)d_in[1];
    const int*   f2c  = (const int*)d_in[2];
    const float* dist = (const float*)d_in[3];
    const float* W1   = (const float*)d_in[4];
    const float* b1   = (const float*)d_in[5];
    const float* W2   = (const float*)d_in[6];
    const float* b2   = (const float*)d_in[7];
    const float* W3   = (const float*)d_in[8];
    const float* b3   = (const float*)d_in[9];
    f16* ws = (f16*)d_ws;

    prep_w<<<256, 256, 0, stream>>>(W1, W2, W3, ws);

    const int n_rows = 2 * NF;                    // 200000
    dim3 grid(n_rows / TM);                       // 3125
    fused_mlp_v17<<<grid, 256, 0, stream>>>(x, xsc, f2c, dist, W1, b1, b2, b3,
                                            ws, (float*)d_out);
}

// Round 18
// 77.063 us; speedup vs baseline: 1.9942x; 1.9942x over previous
//
#include <hip/hip_runtime.h>
#include <math.h>

#define H 128
#define NF 100000
#define NC 25000
#define TM 64

typedef _Float16 f16;
typedef f16 f16x8 __attribute__((ext_vector_type(8)));
typedef f16 f16x4 __attribute__((ext_vector_type(4)));
typedef float f32x4 __attribute__((ext_vector_type(4)));

#define MFMA16(a, b, c) __builtin_amdgcn_mfma_f32_16x16x32_f16((a), (b), (c), 0, 0, 0)

// ws: fragment-ordered f16 weights (fragment = 64 lanes x 8 f16 = 1 KB contiguous)
//   F1 @ 0     : [nt=8][kk=8][lane=64][8]   W1^T, k<256 (kk 0..3 = xg half, 4..7 = xs half)
//   F2 @ 32768 : [nt=8][kk=4][lane=64][8]   W2^T
//   F3 @ 49152 : [nt=8][kk=4][lane=64][8]   W3^T
// fragment element: n = nt*16 + (lane&15), k = kk*32 + (lane>>4)*8 + j

__global__ void prep_w(const float* __restrict__ W1, const float* __restrict__ W2,
                       const float* __restrict__ W3, f16* __restrict__ ws)
{
    int i = blockIdx.x * 256 + threadIdx.x;   // 0..65535, grid exact
    if (i < 32768) {
        int j = i & 7, lane = (i >> 3) & 63, kk = (i >> 9) & 7, nt = i >> 12;
        int n = nt * 16 + (lane & 15);
        int k = kk * 32 + (lane >> 4) * 8 + j;
        ws[i] = (f16)W1[k * H + n];
    } else if (i < 49152) {
        int q = i - 32768;
        int j = q & 7, lane = (q >> 3) & 63, kk = (q >> 9) & 3, nt = q >> 11;
        int n = nt * 16 + (lane & 15);
        int k = kk * 32 + (lane >> 4) * 8 + j;
        ws[i] = (f16)W2[k * H + n];
    } else {
        int q = i - 49152;
        int j = q & 7, lane = (q >> 3) & 63, kk = (q >> 9) & 3, nt = q >> 11;
        int n = nt * 16 + (lane & 15);
        int k = kk * 32 + (lane >> 4) * 8 + j;
        ws[i] = (f16)W3[k * H + n];
    }
}

__device__ __forceinline__ float silu_f(float v) {
    return v / (1.0f + __expf(-v));
}

// R11 structure with NO __launch_bounds__: no compiler residency cap, no VGPR
// squeeze. Natural limits: VGPR ~64 -> 8 waves/SIMD; LDS 16.9 KB -> 9 blocks/CU.
// (R17 proved the 2nd launch_bounds arg caps residency; >4 squeezes VGPR to spill.)
__global__
void fused_mlp_v18(const float* __restrict__ x,     // [2][25000][128]
                   const float* __restrict__ xsc,   // [2][100000][128]
                   const int*   __restrict__ f2c,   // [100000]
                   const float* __restrict__ dist,  // [100000]
                   const float* __restrict__ W1,    // [257][128] (row 256 used as f32)
                   const float* __restrict__ b1,
                   const float* __restrict__ b2,
                   const float* __restrict__ b3,
                   const f16*   __restrict__ ws,
                   float* __restrict__ out)         // [200000][128]
{
    __shared__ __align__(16) f16 sA[TM * H];         // 16 KB
    __shared__ float sD[TM];
    __shared__ int   sCI[TM];

    const int t = threadIdx.x;
    const int l = t & 63, w = t >> 6;
    const int wRow = (w >> 1) * 32;                  // 0 or 32
    const int wnt  = (w & 1) * 4;                    // first n-tile (of 8) for this wave
    const int lr = l & 15, lg = l >> 4;
    const int R0 = blockIdx.x * TM;

    // ---- per-row metadata ----
    if (t < TM) {
        int Rs = R0 + t;
        int bb = Rs >= NF;
        int nn = Rs - bb * NF;
        sCI[t] = bb * NC + f2c[nn];
        sD[t]  = dist[nn];
    }
    __syncthreads();                                 // B0: meta ready

    const f16* F1 = ws;
    const f16* F2 = ws + 32768;
    const f16* F3 = ws + 49152;

    // ---- acc init: b1 + d*W1[256] ----
    f32x4 acc[2][4];
    #pragma unroll
    for (int nt = 0; nt < 4; ++nt) {
        int col = (wnt + nt) * 16 + lr;
        float bc = b1[col];
        float wc = W1[256 * H + col];
        #pragma unroll
        for (int mt = 0; mt < 2; ++mt)
            #pragma unroll
            for (int r = 0; r < 4; ++r)
                acc[mt][nt][r] = bc + sD[wRow + mt * 16 + lg * 4 + r] * wc;
    }

    // ---- phase 1: stage xg (gathered coarse rows) ----
    #pragma unroll
    for (int i = 0; i < 8; ++i) {
        int f = i * 256 + t;
        int row = f >> 5, col = (f & 31) * 4;
        float4 v = *(const float4*)(x + (long long)sCI[row] * H + col);
        f16x4 hv; hv[0] = (f16)v.x; hv[1] = (f16)v.y; hv[2] = (f16)v.z; hv[3] = (f16)v.w;
        *(f16x4*)(sA + row * H + (((col >> 3) ^ (row & 7)) << 3) + (col & 7)) = hv;
    }
    __syncthreads();                                 // B1: xg ready

    // layer-1 half 0 (F1 kk=0..3)
    #pragma unroll
    for (int kk = 0; kk < 4; ++kk) {
        f16x8 wv[4];
        #pragma unroll
        for (int nt = 0; nt < 4; ++nt)
            wv[nt] = *(const f16x8*)(F1 + ((((wnt + nt) * 8 + kk) * 64 + l) << 3));
        int k = kk * 32 + (lg << 3);
        int slot = (((k >> 3) ^ (lr & 7)) << 3);
        f16x8 a0 = *(const f16x8*)(sA + (wRow + lr) * H + slot);
        f16x8 a1 = *(const f16x8*)(sA + (wRow + 16 + lr) * H + slot);
        #pragma unroll
        for (int nt = 0; nt < 4; ++nt) {
            acc[0][nt] = MFMA16(a0, wv[nt], acc[0][nt]);
            acc[1][nt] = MFMA16(a1, wv[nt], acc[1][nt]);
        }
    }
    __syncthreads();                                 // B2: xg reads done

    // ---- phase 2: stage xs into the same buffer ----
    #pragma unroll
    for (int i = 0; i < 8; ++i) {
        int f = i * 256 + t;
        int row = f >> 5, col = (f & 31) * 4;
        float4 v = *(const float4*)(xsc + (long long)(R0 + row) * H + col);
        f16x4 hv; hv[0] = (f16)v.x; hv[1] = (f16)v.y; hv[2] = (f16)v.z; hv[3] = (f16)v.w;
        *(f16x4*)(sA + row * H + (((col >> 3) ^ (row & 7)) << 3) + (col & 7)) = hv;
    }
    __syncthreads();                                 // B3: xs ready

    // layer-1 half 1 (F1 kk=4..7)
    #pragma unroll
    for (int kk = 0; kk < 4; ++kk) {
        f16x8 wv[4];
        #pragma unroll
        for (int nt = 0; nt < 4; ++nt)
            wv[nt] = *(const f16x8*)(F1 + ((((wnt + nt) * 8 + kk + 4) * 64 + l) << 3));
        int k = kk * 32 + (lg << 3);
        int slot = (((k >> 3) ^ (lr & 7)) << 3);
        f16x8 a0 = *(const f16x8*)(sA + (wRow + lr) * H + slot);
        f16x8 a1 = *(const f16x8*)(sA + (wRow + 16 + lr) * H + slot);
        #pragma unroll
        for (int nt = 0; nt < 4; ++nt) {
            acc[0][nt] = MFMA16(a0, wv[nt], acc[0][nt]);
            acc[1][nt] = MFMA16(a1, wv[nt], acc[1][nt]);
        }
    }
    __syncthreads();                                 // B4: xs reads done

    // h1 -> sA
    #pragma unroll
    for (int nt = 0; nt < 4; ++nt)
        #pragma unroll
        for (int mt = 0; mt < 2; ++mt)
            #pragma unroll
            for (int r = 0; r < 4; ++r) {
                int row = wRow + mt * 16 + lg * 4 + r;
                int col = (wnt + nt) * 16 + lr;
                sA[row * H + (((col >> 3) ^ (row & 7)) << 3) + (col & 7)] =
                    (f16)silu_f(acc[mt][nt][r]);
            }
    __syncthreads();                                 // B5: h1 ready

    // ---- layer 2 ----
    #pragma unroll
    for (int nt = 0; nt < 4; ++nt) {
        float bc = b2[(wnt + nt) * 16 + lr];
        #pragma unroll
        for (int mt = 0; mt < 2; ++mt)
            #pragma unroll
            for (int r = 0; r < 4; ++r)
                acc[mt][nt][r] = bc;
    }
    #pragma unroll
    for (int kk = 0; kk < 4; ++kk) {
        f16x8 wv[4];
        #pragma unroll
        for (int nt = 0; nt < 4; ++nt)
            wv[nt] = *(const f16x8*)(F2 + ((((wnt + nt) * 4 + kk) * 64 + l) << 3));
        int k = kk * 32 + (lg << 3);
        int slot = (((k >> 3) ^ (lr & 7)) << 3);
        f16x8 a0 = *(const f16x8*)(sA + (wRow + lr) * H + slot);
        f16x8 a1 = *(const f16x8*)(sA + (wRow + 16 + lr) * H + slot);
        #pragma unroll
        for (int nt = 0; nt < 4; ++nt) {
            acc[0][nt] = MFMA16(a0, wv[nt], acc[0][nt]);
            acc[1][nt] = MFMA16(a1, wv[nt], acc[1][nt]);
        }
    }
    __syncthreads();                                 // B6: h1 reads done

    // h2 -> sA
    #pragma unroll
    for (int nt = 0; nt < 4; ++nt)
        #pragma unroll
        for (int mt = 0; mt < 2; ++mt)
            #pragma unroll
            for (int r = 0; r < 4; ++r) {
                int row = wRow + mt * 16 + lg * 4 + r;
                int col = (wnt + nt) * 16 + lr;
                sA[row * H + (((col >> 3) ^ (row & 7)) << 3) + (col & 7)] =
                    (f16)silu_f(acc[mt][nt][r]);
            }
    __syncthreads();                                 // B7: h2 ready

    // ---- layer 3 ----
    #pragma unroll
    for (int nt = 0; nt < 4; ++nt) {
        float bc = b3[(wnt + nt) * 16 + lr];
        #pragma unroll
        for (int mt = 0; mt < 2; ++mt)
            #pragma unroll
            for (int r = 0; r < 4; ++r)
                acc[mt][nt][r] = bc;
    }
    #pragma unroll
    for (int kk = 0; kk < 4; ++kk) {
        f16x8 wv[4];
        #pragma unroll
        for (int nt = 0; nt < 4; ++nt)
            wv[nt] = *(const f16x8*)(F3 + ((((wnt + nt) * 4 + kk) * 64 + l) << 3));
        int k = kk * 32 + (lg << 3);
        int slot = (((k >> 3) ^ (lr & 7)) << 3);
        f16x8 a0 = *(const f16x8*)(sA + (wRow + lr) * H + slot);
        f16x8 a1 = *(const f16x8*)(sA + (wRow + 16 + lr) * H + slot);
        #pragma unroll
        for (int nt = 0; nt < 4; ++nt) {
            acc[0][nt] = MFMA16(a0, wv[nt], acc[0][nt]);
            acc[1][nt] = MFMA16(a1, wv[nt], acc[1][nt]);
        }
    }

    // ---- store out ----
    #pragma unroll
    for (int mt = 0; mt < 2; ++mt)
        #pragma unroll
        for (int nt = 0; nt < 4; ++nt)
            #pragma unroll
            for (int r = 0; r < 4; ++r) {
                long long row = (long long)R0 + wRow + mt * 16 + lg * 4 + r;
                int col = (wnt + nt) * 16 + lr;
                out[row * H + col] = acc[mt][nt][r];
            }
}

extern "C" void kernel_launch(void* const* d_in, const int* in_sizes, int n_in,
                              void* d_out, int out_size, void* d_ws, size_t ws_size,
                              hipStream_t stream)
{
    const float* x    = (const float*)d_in[0];
    const float* xsc  = (const float*)d_in[1];
    const int*   f2c  = (const int*)d_in[2];
    const float* dist = (const float*)d_in[3];
    const float* W1   = (const float*)d_in[4];
    const float* b1   = (const float*)d_in[5];
    const float* W2   = (const float*)d_in[6];
    const float* b2   = (const float*)d_in[7];
    const float* W3   = (const float*)d_in[8];
    const float* b3   = (const float*)d_in[9];
    f16* ws = (f16*)d_ws;

    prep_w<<<256, 256, 0, stream>>>(W1, W2, W3, ws);

    const int n_rows = 2 * NF;                    // 200000
    dim3 grid(n_rows / TM);                       // 3125
    fused_mlp_v18<<<grid, 256, 0, stream>>>(x, xsc, f2c, dist, W1, b1, b2, b3,
                                            ws, (float*)d_out);
}